// Round 19
// baseline (375.683 us; speedup 1.0000x reference)
//
#include <hip/hip_runtime.h>

typedef __attribute__((ext_vector_type(8))) short short8;
typedef __attribute__((ext_vector_type(4))) float f32x4;

#define C 32
#define T_LEN 65536
#define BATCH 4
#define NLAYERS 20

__device__ inline unsigned short f2bf(float f) {
    unsigned int u = __float_as_uint(f);
    unsigned int r = (u + 0x7fffu + ((u >> 16) & 1u)) >> 16;
    return (unsigned short)r;
}
// packed fp32->bf16 RNE (2 values/inst)
__device__ inline unsigned cvt_pk(float lo, float hi) {
    unsigned r;
    asm("v_cvt_pk_bf16_f32 %0, %1, %2" : "=v"(r) : "v"(lo), "v"(hi));
    return r;
}
__device__ inline float bf2f(unsigned short h) {
    return __uint_as_float((unsigned)h << 16);
}

// ---- weight prep: A-fragment reorder (bf16) ----
__global__ void k_prep(const float* __restrict__ dW, const float* __restrict__ rW,
                       unsigned short* __restrict__ wA1, unsigned short* __restrict__ wA2) {
    int l = blockIdx.x;
    int tid = threadIdx.x;  // 768
    {
        int frag = tid >> 6, lane = tid & 63;   // frag = m*3+kk
        int m = frag / 3, kk = frag % 3;
        int row = lane & 15, g = lane >> 4;
        int o = m * 16 + row;
#pragma unroll
        for (int j = 0; j < 8; ++j) {
            int ch = g * 8 + j;
            float v = dW[(((size_t)l * 64 + o) * 32 + ch) * 3 + kk];
            wA1[(((size_t)l * 12 + frag) * 64 + lane) * 8 + j] = f2bf(v);
        }
    }
    if (tid < 128) {
        int m2 = tid >> 6, lane = tid & 63;
        int row = lane & 15, g = lane >> 4;
        int o = m2 * 16 + row;
#pragma unroll
        for (int j = 0; j < 8; ++j) {
            int ch = g * 8 + j;
            float v = rW[((size_t)l * 32 + o) * 32 + ch];
            wA2[(((size_t)l * 2 + m2) * 64 + lane) * 8 + j] = f2bf(v);
        }
    }
}

// ---- input 1x1 conv: bf16 act stream only ----
__global__ __launch_bounds__(256) void k_in(const float* __restrict__ x,
        const float* __restrict__ inW, const float* __restrict__ inb,
        unsigned short* __restrict__ act, float* __restrict__ skip) {
    int i = blockIdx.x * 256 + threadIdx.x;   // over T*16
    int b = blockIdx.y;
    int t = i >> 4, q = i & 15;
    float xv = x[(size_t)b * T_LEN + t];
    int c0 = q * 2;
    float a0 = fmaf(inW[c0], xv, inb[c0]);
    float a1 = fmaf(inW[c0 + 1], xv, inb[c0 + 1]);
    size_t base = ((size_t)b * T_LEN + t) * C + c0;
    ((unsigned int*)act)[base >> 1] = ((unsigned)f2bf(a1) << 16) | (unsigned)f2bf(a0);
    if (q == 0) skip[(size_t)b * T_LEN + t] = 0.f;
}

// ---- one WaveNet layer (bf16 residual stream; weights staged in LDS) ----
__global__ __launch_bounds__(256) void k_layer(
        const unsigned short* __restrict__ actIn, unsigned short* __restrict__ actOut,
        float* __restrict__ skip,
        const unsigned short* __restrict__ wA1, const unsigned short* __restrict__ wA2,
        const float* __restrict__ db, const float* __restrict__ rb,
        const float* __restrict__ pW, const float* __restrict__ pbF, int d) {
    // weight block: wA1 = 12*64*8 = 6144 shorts, wA2 = 2*64*8 = 1024 shorts
    __shared__ __align__(16) unsigned short wlds[7168];   // 14336 B

    int tid = threadIdx.x;
    int wv = tid >> 6, l = tid & 63;
    int n = l & 15, g = l >> 4;

    // stage weights once per block (linear uint4 copy; all 4 waves share)
    {
        const uint4* s1 = (const uint4*)wA1;   // 768 uint4
        const uint4* s2 = (const uint4*)wA2;   // 128 uint4
        uint4* dstv = (uint4*)wlds;
        for (int i = tid; i < 896; i += 256)
            dstv[i] = (i < 768) ? s1[i] : s2[i - 768];
    }
    __syncthreads();

    // chunked XCD swizzle: phys round-robin -> contiguous t-chunks per XCD
    int flat = blockIdx.x;                      // 0..1023
    int lb = (flat & 7) * 128 + (flat >> 3);
    int b = lb >> 8;
    int t_base = (lb & 255) * 256 + wv * 64;

    short8 a1[12], a2[2];
#pragma unroll
    for (int f = 0; f < 12; ++f)
        a1[f] = *(const short8*)(wlds + (f * 64 + l) * 8);
#pragma unroll
    for (int m2 = 0; m2 < 2; ++m2)
        a2[m2] = *(const short8*)(wlds + 6144 + (m2 * 64 + l) * 8);

    f32x4 dbv[4], rbv[2], pwv[2];
#pragma unroll
    for (int m = 0; m < 4; ++m) dbv[m] = *(const f32x4*)(db + m * 16 + g * 4);
#pragma unroll
    for (int m2 = 0; m2 < 2; ++m2) rbv[m2] = *(const f32x4*)(rb + m2 * 16 + g * 4);
#pragma unroll
    for (int m = 0; m < 2; ++m) pwv[m] = *(const f32x4*)(pW + m * 16 + g * 4);

    int srcE = ((g & 1) << 5) | n;
    int srcO = srcE + 16;
    bool hi = (g >= 2);

    const unsigned short* actB = actIn + (size_t)b * T_LEN * C + g * 8;
    const short8 zero8 = {0, 0, 0, 0, 0, 0, 0, 0};

    // prologue: taps for nf=0
    short8 tc[3], tn[3];
    {
        int t = t_base + n;
#pragma unroll
        for (int kk = 0; kk < 3; ++kk) {
            int tt = t - (2 - kk) * d;
            tc[kk] = (tt >= 0) ? *(const short8*)(actB + (size_t)tt * C) : zero8;
        }
    }

#pragma unroll
    for (int nf = 0; nf < 4; ++nf) {
        int t = t_base + nf * 16 + n;
        size_t rowbase = ((size_t)b * T_LEN + t) * C;

        // prefetch next iteration's taps (1-deep pipeline)
        if (nf < 3) {
            int t1 = t + 16;
#pragma unroll
            for (int kk = 0; kk < 3; ++kk) {
                int tt = t1 - (2 - kk) * d;
                tn[kk] = (tt >= 0) ? *(const short8*)(actB + (size_t)tt * C) : zero8;
            }
        }

        // C-in for GEMM2: bf16 residual re-read from the current act row
        union { unsigned long long u; unsigned short s[4]; } ci[2];
        if (actOut) {
#pragma unroll
            for (int m2 = 0; m2 < 2; ++m2)
                ci[m2].u = *(const unsigned long long*)(actIn + rowbase + m2 * 16 + g * 4);
        }

        // ---- GEMM1: Y[64,16] = W[64x96] * X[96,16] ----
        f32x4 zf = {0.f, 0.f, 0.f, 0.f};
        f32x4 y[4] = {zf, zf, zf, zf};
#pragma unroll
        for (int kk = 0; kk < 3; ++kk)
#pragma unroll
            for (int m = 0; m < 4; ++m)
                y[m] = __builtin_amdgcn_mfma_f32_16x16x32_bf16(a1[m * 3 + kk], tc[kk], y[m], 0, 0, 0);

        // ---- gating: tanh(yt)*sigm(ys) = (1-A)/((1+A)(1+B)) ----
        float sk[2][4];
        float sacc = 0.f;
#pragma unroll
        for (int m2 = 0; m2 < 2; ++m2)
#pragma unroll
            for (int r = 0; r < 4; ++r) {
                float yt = y[m2][r] + dbv[m2][r];
                float ys = y[m2 + 2][r] + dbv[m2 + 2][r];
                float A = __expf(fminf(-2.f * yt, 40.f));
                float B = __expf(fminf(-ys, 40.f));
                float s = (1.f - A) * __fdividef(1.f, (1.f + A) * (1.f + B));
                sk[m2][r] = s;
                sacc = fmaf(pwv[m2][r], s, sacc);
            }

        sacc += __shfl_xor(sacc, 16, 64);
        sacc += __shfl_xor(sacc, 32, 64);
        if (l < 16) {
            size_t sidx = (size_t)b * T_LEN + t;
            float v = skip[sidx] + sacc;
            if (pbF) v += pbF[0];
            skip[sidx] = v;
        }

        // ---- GEMM2 (skipped on the last layer: residual output is dead) ----
        if (actOut) {
            unsigned h0[2], h1[2];
#pragma unroll
            for (int r2 = 0; r2 < 2; ++r2) {
                h0[r2] = cvt_pk(sk[0][r2 * 2], sk[0][r2 * 2 + 1]);
                h1[r2] = cvt_pk(sk[1][r2 * 2], sk[1][r2 * 2 + 1]);
            }
            union { short8 v; unsigned u[4]; } B2;
#pragma unroll
            for (int q = 0; q < 2; ++q) {
                unsigned e0 = (unsigned)__shfl((int)h0[q], srcE, 64);
                unsigned e1 = (unsigned)__shfl((int)h1[q], srcE, 64);
                unsigned o0 = (unsigned)__shfl((int)h0[q], srcO, 64);
                unsigned o1 = (unsigned)__shfl((int)h1[q], srcO, 64);
                B2.u[q]     = hi ? e1 : e0;
                B2.u[q + 2] = hi ? o1 : o0;
            }
#pragma unroll
            for (int m2 = 0; m2 < 2; ++m2) {
                f32x4 c2;
#pragma unroll
                for (int r = 0; r < 4; ++r) c2[r] = bf2f(ci[m2].s[r]);
                c2 += rbv[m2];
                f32x4 d2 = __builtin_amdgcn_mfma_f32_16x16x32_bf16(a2[m2], B2.v, c2, 0, 0, 0);
                unsigned lo  = cvt_pk(d2[0], d2[1]);
                unsigned hi2 = cvt_pk(d2[2], d2[3]);
                unsigned long long pk = ((unsigned long long)hi2 << 32) | lo;
                *(unsigned long long*)(actOut + rowbase + m2 * 16 + g * 4) = pk;
            }
        }

        if (nf < 3) { tc[0] = tn[0]; tc[1] = tn[1]; tc[2] = tn[2]; }
    }
}

extern "C" void kernel_launch(void* const* d_in, const int* in_sizes, int n_in,
                              void* d_out, int out_size, void* d_ws, size_t ws_size,
                              hipStream_t stream) {
    const float* x      = (const float*)d_in[0];
    const float* in_W   = (const float*)d_in[1];
    const float* in_b   = (const float*)d_in[2];
    const float* dil_W  = (const float*)d_in[3];
    const float* dil_b  = (const float*)d_in[4];
    const float* res_W  = (const float*)d_in[5];
    const float* res_b  = (const float*)d_in[6];
    const float* post_W = (const float*)d_in[7];
    const float* post_b = (const float*)d_in[8];

    const size_t act_elems = (size_t)BATCH * T_LEN * C;
    unsigned short* actA = (unsigned short*)d_ws;
    unsigned short* actB = actA + act_elems;
    unsigned short* wA1 = actB + act_elems;
    unsigned short* wA2 = wA1 + (size_t)NLAYERS * 12 * 64 * 8;
    float* skip = (float*)d_out;

    k_prep<<<NLAYERS, 768, 0, stream>>>(dil_W, res_W, wA1, wA2);

    dim3 gin(T_LEN * 16 / 256, BATCH);
    k_in<<<gin, 256, 0, stream>>>(x, in_W, in_b, actA, skip);

    const unsigned short* cur = actA;
    unsigned short* nxt = actB;
    for (int l = 0; l < NLAYERS; ++l) {
        int d = 1 << (l % 10);
        bool last = (l == NLAYERS - 1);
        k_layer<<<1024, 256, 0, stream>>>(cur, last ? nullptr : nxt,
                skip,
                wA1 + (size_t)l * 12 * 64 * 8,
                wA2 + (size_t)l * 2 * 64 * 8,
                dil_b + (size_t)l * 64,
                res_b + (size_t)l * C,
                post_W + (size_t)l * C,
                last ? post_b : (const float*)nullptr,
                d);
        unsigned short* tmp = nxt;
        nxt = (unsigned short*)cur;
        cur = tmp;
    }
}

// Round 20
// 374.093 us; speedup vs baseline: 1.0042x; 1.0042x over previous
//
#include <hip/hip_runtime.h>

typedef __attribute__((ext_vector_type(8))) short short8;
typedef __attribute__((ext_vector_type(4))) float f32x4;

#define C 32
#define T_LEN 65536
#define BATCH 4
#define NLAYERS 20

__device__ inline unsigned short f2bf(float f) {
    unsigned int u = __float_as_uint(f);
    unsigned int r = (u + 0x7fffu + ((u >> 16) & 1u)) >> 16;
    return (unsigned short)r;
}
// packed fp32->bf16 RNE (2 values/inst)
__device__ inline unsigned cvt_pk(float lo, float hi) {
    unsigned r;
    asm("v_cvt_pk_bf16_f32 %0, %1, %2" : "=v"(r) : "v"(lo), "v"(hi));
    return r;
}
__device__ inline float bf2f(unsigned short h) {
    return __uint_as_float((unsigned)h << 16);
}

// ---- weight prep: A-fragment reorder (bf16) ----
__global__ void k_prep(const float* __restrict__ dW, const float* __restrict__ rW,
                       unsigned short* __restrict__ wA1, unsigned short* __restrict__ wA2) {
    int l = blockIdx.x;
    int tid = threadIdx.x;  // 768
    {
        int frag = tid >> 6, lane = tid & 63;   // frag = m*3+kk
        int m = frag / 3, kk = frag % 3;
        int row = lane & 15, g = lane >> 4;
        int o = m * 16 + row;
#pragma unroll
        for (int j = 0; j < 8; ++j) {
            int ch = g * 8 + j;
            float v = dW[(((size_t)l * 64 + o) * 32 + ch) * 3 + kk];
            wA1[(((size_t)l * 12 + frag) * 64 + lane) * 8 + j] = f2bf(v);
        }
    }
    if (tid < 128) {
        int m2 = tid >> 6, lane = tid & 63;
        int row = lane & 15, g = lane >> 4;
        int o = m2 * 16 + row;
#pragma unroll
        for (int j = 0; j < 8; ++j) {
            int ch = g * 8 + j;
            float v = rW[((size_t)l * 32 + o) * 32 + ch];
            wA2[(((size_t)l * 2 + m2) * 64 + lane) * 8 + j] = f2bf(v);
        }
    }
}

// ---- input 1x1 conv: bf16 act stream only ----
__global__ __launch_bounds__(256) void k_in(const float* __restrict__ x,
        const float* __restrict__ inW, const float* __restrict__ inb,
        unsigned short* __restrict__ act, float* __restrict__ skip) {
    int i = blockIdx.x * 256 + threadIdx.x;   // over T*16
    int b = blockIdx.y;
    int t = i >> 4, q = i & 15;
    float xv = x[(size_t)b * T_LEN + t];
    int c0 = q * 2;
    float a0 = fmaf(inW[c0], xv, inb[c0]);
    float a1 = fmaf(inW[c0 + 1], xv, inb[c0 + 1]);
    size_t base = ((size_t)b * T_LEN + t) * C + c0;
    ((unsigned int*)act)[base >> 1] = ((unsigned)f2bf(a1) << 16) | (unsigned)f2bf(a0);
    if (q == 0) skip[(size_t)b * T_LEN + t] = 0.f;
}

// ---- one WaveNet layer (bf16 residual stream; C-in re-derived from act row) ----
__global__ __launch_bounds__(256) void k_layer(
        const unsigned short* __restrict__ actIn, unsigned short* __restrict__ actOut,
        float* __restrict__ skip,
        const unsigned short* __restrict__ wA1, const unsigned short* __restrict__ wA2,
        const float* __restrict__ db, const float* __restrict__ rb,
        const float* __restrict__ pW, const float* __restrict__ pbF, int d) {
    int tid = threadIdx.x;
    int wv = tid >> 6, l = tid & 63;
    int n = l & 15, g = l >> 4;

    // chunked XCD swizzle: phys round-robin -> contiguous t-chunks per XCD
    int flat = blockIdx.x;                      // 0..1023
    int lb = (flat & 7) * 128 + (flat >> 3);
    int b = lb >> 8;
    int t_base = (lb & 255) * 256 + wv * 64;

    short8 a1[12], a2[2];
#pragma unroll
    for (int f = 0; f < 12; ++f)
        a1[f] = *(const short8*)(wA1 + ((size_t)f * 64 + l) * 8);
#pragma unroll
    for (int m2 = 0; m2 < 2; ++m2)
        a2[m2] = *(const short8*)(wA2 + ((size_t)m2 * 64 + l) * 8);

    f32x4 dbv[4], rbv[2], pwv[2];
#pragma unroll
    for (int m = 0; m < 4; ++m) dbv[m] = *(const f32x4*)(db + m * 16 + g * 4);
#pragma unroll
    for (int m2 = 0; m2 < 2; ++m2) rbv[m2] = *(const f32x4*)(rb + m2 * 16 + g * 4);
#pragma unroll
    for (int m = 0; m < 2; ++m) pwv[m] = *(const f32x4*)(pW + m * 16 + g * 4);

    int srcE = ((g & 1) << 5) | n;
    int srcO = srcE + 16;
    bool hi = (g >= 2);

    const unsigned short* actB = actIn + (size_t)b * T_LEN * C + g * 8;
    const short8 zero8 = {0, 0, 0, 0, 0, 0, 0, 0};

    // prologue: taps for nf=0
    short8 tc[3], tn[3];
    {
        int t = t_base + n;
#pragma unroll
        for (int kk = 0; kk < 3; ++kk) {
            int tt = t - (2 - kk) * d;
            tc[kk] = (tt >= 0) ? *(const short8*)(actB + (size_t)tt * C) : zero8;
        }
    }

#pragma unroll
    for (int nf = 0; nf < 4; ++nf) {
        int t = t_base + nf * 16 + n;
        size_t rowbase = ((size_t)b * T_LEN + t) * C;

        // prefetch next iteration's taps (1-deep pipeline)
        if (nf < 3) {
            int t1 = t + 16;
#pragma unroll
            for (int kk = 0; kk < 3; ++kk) {
                int tt = t1 - (2 - kk) * d;
                tn[kk] = (tt >= 0) ? *(const short8*)(actB + (size_t)tt * C) : zero8;
            }
        }

        // C-in for GEMM2: bf16 residual re-read from the current act row
        union { unsigned long long u; unsigned short s[4]; } ci[2];
        if (actOut) {
#pragma unroll
            for (int m2 = 0; m2 < 2; ++m2)
                ci[m2].u = *(const unsigned long long*)(actIn + rowbase + m2 * 16 + g * 4);
        }

        // ---- GEMM1: Y[64,16] = W[64x96] * X[96,16] ----
        f32x4 zf = {0.f, 0.f, 0.f, 0.f};
        f32x4 y[4] = {zf, zf, zf, zf};
#pragma unroll
        for (int kk = 0; kk < 3; ++kk)
#pragma unroll
            for (int m = 0; m < 4; ++m)
                y[m] = __builtin_amdgcn_mfma_f32_16x16x32_bf16(a1[m * 3 + kk], tc[kk], y[m], 0, 0, 0);

        // ---- gating: tanh(yt)*sigm(ys) = (1-A)/((1+A)(1+B)) ----
        float sk[2][4];
        float sacc = 0.f;
#pragma unroll
        for (int m2 = 0; m2 < 2; ++m2)
#pragma unroll
            for (int r = 0; r < 4; ++r) {
                float yt = y[m2][r] + dbv[m2][r];
                float ys = y[m2 + 2][r] + dbv[m2 + 2][r];
                float A = __expf(fminf(-2.f * yt, 40.f));
                float B = __expf(fminf(-ys, 40.f));
                float s = (1.f - A) * __fdividef(1.f, (1.f + A) * (1.f + B));
                sk[m2][r] = s;
                sacc = fmaf(pwv[m2][r], s, sacc);
            }

        sacc += __shfl_xor(sacc, 16, 64);
        sacc += __shfl_xor(sacc, 32, 64);
        if (l < 16) {
            size_t sidx = (size_t)b * T_LEN + t;
            float v = skip[sidx] + sacc;
            if (pbF) v += pbF[0];
            skip[sidx] = v;
        }

        // ---- GEMM2 (skipped on the last layer: residual output is dead) ----
        if (actOut) {
            unsigned h0[2], h1[2];
#pragma unroll
            for (int r2 = 0; r2 < 2; ++r2) {
                h0[r2] = cvt_pk(sk[0][r2 * 2], sk[0][r2 * 2 + 1]);
                h1[r2] = cvt_pk(sk[1][r2 * 2], sk[1][r2 * 2 + 1]);
            }
            union { short8 v; unsigned u[4]; } B2;
#pragma unroll
            for (int q = 0; q < 2; ++q) {
                unsigned e0 = (unsigned)__shfl((int)h0[q], srcE, 64);
                unsigned e1 = (unsigned)__shfl((int)h1[q], srcE, 64);
                unsigned o0 = (unsigned)__shfl((int)h0[q], srcO, 64);
                unsigned o1 = (unsigned)__shfl((int)h1[q], srcO, 64);
                B2.u[q]     = hi ? e1 : e0;
                B2.u[q + 2] = hi ? o1 : o0;
            }
#pragma unroll
            for (int m2 = 0; m2 < 2; ++m2) {
                f32x4 c2;
#pragma unroll
                for (int r = 0; r < 4; ++r) c2[r] = bf2f(ci[m2].s[r]);
                c2 += rbv[m2];
                f32x4 d2 = __builtin_amdgcn_mfma_f32_16x16x32_bf16(a2[m2], B2.v, c2, 0, 0, 0);
                unsigned lo  = cvt_pk(d2[0], d2[1]);
                unsigned hi2 = cvt_pk(d2[2], d2[3]);
                unsigned long long pk = ((unsigned long long)hi2 << 32) | lo;
                *(unsigned long long*)(actOut + rowbase + m2 * 16 + g * 4) = pk;
            }
        }

        if (nf < 3) { tc[0] = tn[0]; tc[1] = tn[1]; tc[2] = tn[2]; }
    }
}

extern "C" void kernel_launch(void* const* d_in, const int* in_sizes, int n_in,
                              void* d_out, int out_size, void* d_ws, size_t ws_size,
                              hipStream_t stream) {
    const float* x      = (const float*)d_in[0];
    const float* in_W   = (const float*)d_in[1];
    const float* in_b   = (const float*)d_in[2];
    const float* dil_W  = (const float*)d_in[3];
    const float* dil_b  = (const float*)d_in[4];
    const float* res_W  = (const float*)d_in[5];
    const float* res_b  = (const float*)d_in[6];
    const float* post_W = (const float*)d_in[7];
    const float* post_b = (const float*)d_in[8];

    const size_t act_elems = (size_t)BATCH * T_LEN * C;
    unsigned short* actA = (unsigned short*)d_ws;
    unsigned short* actB = actA + act_elems;
    unsigned short* wA1 = actB + act_elems;
    unsigned short* wA2 = wA1 + (size_t)NLAYERS * 12 * 64 * 8;
    float* skip = (float*)d_out;

    k_prep<<<NLAYERS, 768, 0, stream>>>(dil_W, res_W, wA1, wA2);

    dim3 gin(T_LEN * 16 / 256, BATCH);
    k_in<<<gin, 256, 0, stream>>>(x, in_W, in_b, actA, skip);

    const unsigned short* cur = actA;
    unsigned short* nxt = actB;
    for (int l = 0; l < NLAYERS; ++l) {
        int d = 1 << (l % 10);
        bool last = (l == NLAYERS - 1);
        k_layer<<<1024, 256, 0, stream>>>(cur, last ? nullptr : nxt,
                skip,
                wA1 + (size_t)l * 12 * 64 * 8,
                wA2 + (size_t)l * 2 * 64 * 8,
                dil_b + (size_t)l * 64,
                res_b + (size_t)l * C,
                post_W + (size_t)l * C,
                last ? post_b : (const float*)nullptr,
                d);
        unsigned short* tmp = nxt;
        nxt = (unsigned short*)cur;
        cur = tmp;
    }
}

// Round 21
// 371.431 us; speedup vs baseline: 1.0114x; 1.0072x over previous
//
#include <hip/hip_runtime.h>

typedef __attribute__((ext_vector_type(8))) short short8;
typedef __attribute__((ext_vector_type(4))) float f32x4;

#define C 32
#define T_LEN 65536
#define BATCH 4
#define NLAYERS 20

__device__ inline unsigned short f2bf(float f) {
    unsigned int u = __float_as_uint(f);
    unsigned int r = (u + 0x7fffu + ((u >> 16) & 1u)) >> 16;
    return (unsigned short)r;
}
// packed fp32->bf16 RNE (2 values/inst)
__device__ inline unsigned cvt_pk(float lo, float hi) {
    unsigned r;
    asm("v_cvt_pk_bf16_f32 %0, %1, %2" : "=v"(r) : "v"(lo), "v"(hi));
    return r;
}
__device__ inline float bf2f(unsigned short h) {
    return __uint_as_float((unsigned)h << 16);
}

// ---- weight prep: A-fragment reorder (bf16) ----
__global__ void k_prep(const float* __restrict__ dW, const float* __restrict__ rW,
                       unsigned short* __restrict__ wA1, unsigned short* __restrict__ wA2) {
    int l = blockIdx.x;
    int tid = threadIdx.x;  // 768
    {
        int frag = tid >> 6, lane = tid & 63;   // frag = m*3+kk
        int m = frag / 3, kk = frag % 3;
        int row = lane & 15, g = lane >> 4;
        int o = m * 16 + row;
#pragma unroll
        for (int j = 0; j < 8; ++j) {
            int ch = g * 8 + j;
            float v = dW[(((size_t)l * 64 + o) * 32 + ch) * 3 + kk];
            wA1[(((size_t)l * 12 + frag) * 64 + lane) * 8 + j] = f2bf(v);
        }
    }
    if (tid < 128) {
        int m2 = tid >> 6, lane = tid & 63;
        int row = lane & 15, g = lane >> 4;
        int o = m2 * 16 + row;
#pragma unroll
        for (int j = 0; j < 8; ++j) {
            int ch = g * 8 + j;
            float v = rW[((size_t)l * 32 + o) * 32 + ch];
            wA2[(((size_t)l * 2 + m2) * 64 + lane) * 8 + j] = f2bf(v);
        }
    }
}

// ---- input 1x1 conv: bf16 act stream only ----
__global__ __launch_bounds__(256) void k_in(const float* __restrict__ x,
        const float* __restrict__ inW, const float* __restrict__ inb,
        unsigned short* __restrict__ act, float* __restrict__ skip) {
    int i = blockIdx.x * 256 + threadIdx.x;   // over T*16
    int b = blockIdx.y;
    int t = i >> 4, q = i & 15;
    float xv = x[(size_t)b * T_LEN + t];
    int c0 = q * 2;
    float a0 = fmaf(inW[c0], xv, inb[c0]);
    float a1 = fmaf(inW[c0 + 1], xv, inb[c0 + 1]);
    size_t base = ((size_t)b * T_LEN + t) * C + c0;
    ((unsigned int*)act)[base >> 1] = ((unsigned)f2bf(a1) << 16) | (unsigned)f2bf(a0);
    if (q == 0) skip[(size_t)b * T_LEN + t] = 0.f;
}

// ---- one WaveNet layer (bf16 residual stream; 2048 blocks, nf=2 for TLP) ----
__global__ __launch_bounds__(256) void k_layer(
        const unsigned short* __restrict__ actIn, unsigned short* __restrict__ actOut,
        float* __restrict__ skip,
        const unsigned short* __restrict__ wA1, const unsigned short* __restrict__ wA2,
        const float* __restrict__ db, const float* __restrict__ rb,
        const float* __restrict__ pW, const float* __restrict__ pbF, int d) {
    int tid = threadIdx.x;
    int wv = tid >> 6, l = tid & 63;
    int n = l & 15, g = l >> 4;

    // chunked XCD swizzle (bijective over 0..2047): contiguous t-chunks per XCD
    int flat = blockIdx.x;                      // 0..2047
    int lb = (flat & 7) * 256 + (flat >> 3);
    int b = lb >> 9;
    int t_base = (lb & 511) * 128 + wv * 32;    // each wave owns 32 t (nf=2)

    short8 a1[12], a2[2];
#pragma unroll
    for (int f = 0; f < 12; ++f)
        a1[f] = *(const short8*)(wA1 + ((size_t)f * 64 + l) * 8);
#pragma unroll
    for (int m2 = 0; m2 < 2; ++m2)
        a2[m2] = *(const short8*)(wA2 + ((size_t)m2 * 64 + l) * 8);

    f32x4 dbv[4], rbv[2], pwv[2];
#pragma unroll
    for (int m = 0; m < 4; ++m) dbv[m] = *(const f32x4*)(db + m * 16 + g * 4);
#pragma unroll
    for (int m2 = 0; m2 < 2; ++m2) rbv[m2] = *(const f32x4*)(rb + m2 * 16 + g * 4);
#pragma unroll
    for (int m = 0; m < 2; ++m) pwv[m] = *(const f32x4*)(pW + m * 16 + g * 4);

    int srcE = ((g & 1) << 5) | n;
    int srcO = srcE + 16;
    bool hi = (g >= 2);

    const unsigned short* actB = actIn + (size_t)b * T_LEN * C + g * 8;
    const short8 zero8 = {0, 0, 0, 0, 0, 0, 0, 0};

    // prologue: taps for nf=0
    short8 tc[3], tn[3];
    {
        int t = t_base + n;
#pragma unroll
        for (int kk = 0; kk < 3; ++kk) {
            int tt = t - (2 - kk) * d;
            tc[kk] = (tt >= 0) ? *(const short8*)(actB + (size_t)tt * C) : zero8;
        }
    }

#pragma unroll
    for (int nf = 0; nf < 2; ++nf) {
        int t = t_base + nf * 16 + n;
        size_t rowbase = ((size_t)b * T_LEN + t) * C;

        // prefetch next iteration's taps (1-deep pipeline)
        if (nf < 1) {
            int t1 = t + 16;
#pragma unroll
            for (int kk = 0; kk < 3; ++kk) {
                int tt = t1 - (2 - kk) * d;
                tn[kk] = (tt >= 0) ? *(const short8*)(actB + (size_t)tt * C) : zero8;
            }
        }

        // C-in for GEMM2: bf16 residual re-read from the current act row
        union { unsigned long long u; unsigned short s[4]; } ci[2];
        if (actOut) {
#pragma unroll
            for (int m2 = 0; m2 < 2; ++m2)
                ci[m2].u = *(const unsigned long long*)(actIn + rowbase + m2 * 16 + g * 4);
        }

        // ---- GEMM1: Y[64,16] = W[64x96] * X[96,16] ----
        f32x4 zf = {0.f, 0.f, 0.f, 0.f};
        f32x4 y[4] = {zf, zf, zf, zf};
#pragma unroll
        for (int kk = 0; kk < 3; ++kk)
#pragma unroll
            for (int m = 0; m < 4; ++m)
                y[m] = __builtin_amdgcn_mfma_f32_16x16x32_bf16(a1[m * 3 + kk], tc[kk], y[m], 0, 0, 0);

        // ---- gating: tanh(yt)*sigm(ys) = (1-A)/((1+A)(1+B)) ----
        float sk[2][4];
        float sacc = 0.f;
#pragma unroll
        for (int m2 = 0; m2 < 2; ++m2)
#pragma unroll
            for (int r = 0; r < 4; ++r) {
                float yt = y[m2][r] + dbv[m2][r];
                float ys = y[m2 + 2][r] + dbv[m2 + 2][r];
                float A = __expf(fminf(-2.f * yt, 40.f));
                float B = __expf(fminf(-ys, 40.f));
                float s = (1.f - A) * __fdividef(1.f, (1.f + A) * (1.f + B));
                sk[m2][r] = s;
                sacc = fmaf(pwv[m2][r], s, sacc);
            }

        sacc += __shfl_xor(sacc, 16, 64);
        sacc += __shfl_xor(sacc, 32, 64);
        if (l < 16) {
            size_t sidx = (size_t)b * T_LEN + t;
            float v = skip[sidx] + sacc;
            if (pbF) v += pbF[0];
            skip[sidx] = v;
        }

        // ---- GEMM2 (skipped on the last layer: residual output is dead) ----
        if (actOut) {
            unsigned h0[2], h1[2];
#pragma unroll
            for (int r2 = 0; r2 < 2; ++r2) {
                h0[r2] = cvt_pk(sk[0][r2 * 2], sk[0][r2 * 2 + 1]);
                h1[r2] = cvt_pk(sk[1][r2 * 2], sk[1][r2 * 2 + 1]);
            }
            union { short8 v; unsigned u[4]; } B2;
#pragma unroll
            for (int q = 0; q < 2; ++q) {
                unsigned e0 = (unsigned)__shfl((int)h0[q], srcE, 64);
                unsigned e1 = (unsigned)__shfl((int)h1[q], srcE, 64);
                unsigned o0 = (unsigned)__shfl((int)h0[q], srcO, 64);
                unsigned o1 = (unsigned)__shfl((int)h1[q], srcO, 64);
                B2.u[q]     = hi ? e1 : e0;
                B2.u[q + 2] = hi ? o1 : o0;
            }
#pragma unroll
            for (int m2 = 0; m2 < 2; ++m2) {
                f32x4 c2;
#pragma unroll
                for (int r = 0; r < 4; ++r) c2[r] = bf2f(ci[m2].s[r]);
                c2 += rbv[m2];
                f32x4 d2 = __builtin_amdgcn_mfma_f32_16x16x32_bf16(a2[m2], B2.v, c2, 0, 0, 0);
                unsigned lo  = cvt_pk(d2[0], d2[1]);
                unsigned hi2 = cvt_pk(d2[2], d2[3]);
                unsigned long long pk = ((unsigned long long)hi2 << 32) | lo;
                *(unsigned long long*)(actOut + rowbase + m2 * 16 + g * 4) = pk;
            }
        }

        if (nf < 1) { tc[0] = tn[0]; tc[1] = tn[1]; tc[2] = tn[2]; }
    }
}

extern "C" void kernel_launch(void* const* d_in, const int* in_sizes, int n_in,
                              void* d_out, int out_size, void* d_ws, size_t ws_size,
                              hipStream_t stream) {
    const float* x      = (const float*)d_in[0];
    const float* in_W   = (const float*)d_in[1];
    const float* in_b   = (const float*)d_in[2];
    const float* dil_W  = (const float*)d_in[3];
    const float* dil_b  = (const float*)d_in[4];
    const float* res_W  = (const float*)d_in[5];
    const float* res_b  = (const float*)d_in[6];
    const float* post_W = (const float*)d_in[7];
    const float* post_b = (const float*)d_in[8];

    const size_t act_elems = (size_t)BATCH * T_LEN * C;
    unsigned short* actA = (unsigned short*)d_ws;
    unsigned short* actB = actA + act_elems;
    unsigned short* wA1 = actB + act_elems;
    unsigned short* wA2 = wA1 + (size_t)NLAYERS * 12 * 64 * 8;
    float* skip = (float*)d_out;

    k_prep<<<NLAYERS, 768, 0, stream>>>(dil_W, res_W, wA1, wA2);

    dim3 gin(T_LEN * 16 / 256, BATCH);
    k_in<<<gin, 256, 0, stream>>>(x, in_W, in_b, actA, skip);

    const unsigned short* cur = actA;
    unsigned short* nxt = actB;
    for (int l = 0; l < NLAYERS; ++l) {
        int d = 1 << (l % 10);
        bool last = (l == NLAYERS - 1);
        k_layer<<<2048, 256, 0, stream>>>(cur, last ? nullptr : nxt,
                skip,
                wA1 + (size_t)l * 12 * 64 * 8,
                wA2 + (size_t)l * 2 * 64 * 8,
                dil_b + (size_t)l * 64,
                res_b + (size_t)l * C,
                post_W + (size_t)l * C,
                last ? post_b : (const float*)nullptr,
                d);
        unsigned short* tmp = nxt;
        nxt = (unsigned short*)cur;
        cur = tmp;
    }
}